// Round 1
// baseline (296.155 us; speedup 1.0000x reference)
//
#include <hip/hip_runtime.h>
#include <hip/hip_bf16.h>
#include <hip/hip_fp16.h>

#define N_SAMP 8192
#define C_CLS  1000
#define A_DIM  2048
#define KDIM   4096   // 2*A_DIM (term1 | term3 folded)
#define CP     1024   // padded C

typedef _Float16 half8 __attribute__((ext_vector_type(8)));
typedef float    f32x4 __attribute__((ext_vector_type(4)));

// Build A' = [cv | -2*fc*cv], B' = [fc^2 | fc] as f16, zero-padded to CP rows.
__global__ __launch_bounds__(256) void prep_kernel(const float* __restrict__ fc,
                                                   const float* __restrict__ cv,
                                                   _Float16* __restrict__ Abuf,
                                                   _Float16* __restrict__ Bbuf) {
    int idx = blockIdx.x * 256 + threadIdx.x;   // over CP*KDIM
    int c = idx >> 12;          // KDIM = 4096
    int k = idx & (KDIM - 1);
    float a = 0.f, b = 0.f;
    if (c < C_CLS) {
        int kk = (k < A_DIM) ? k : (k - A_DIM);
        float cvv = cv[c * A_DIM + kk];
        float f   = fc[c * A_DIM + kk];
        if (k < A_DIM) { a = cvv;            b = f * f; }
        else           { a = -2.f * f * cvv; b = f;     }
    }
    Abuf[idx] = (_Float16)a;
    Bbuf[idx] = (_Float16)b;
}

// S = A' * B'^T  (CP x CP, K = KDIM).  64x64 block tile, 4 waves of 32x32.
__global__ __launch_bounds__(256) void gemm_kernel(const _Float16* __restrict__ A,
                                                   const _Float16* __restrict__ B,
                                                   float* __restrict__ S) {
    int lane = threadIdx.x & 63;
    int w    = threadIdx.x >> 6;        // 0..3
    int wr   = w >> 1, wc = w & 1;
    int c0 = blockIdx.y * 64 + wr * 32;
    int j0 = blockIdx.x * 64 + wc * 32;
    int row  = lane & 15;
    int kgrp = (lane >> 4) * 8;

    f32x4 acc[2][2] = {};
    for (int kk = 0; kk < KDIM; kk += 32) {
        half8 a0 = *(const half8*)(A + (size_t)(c0 +      row) * KDIM + kk + kgrp);
        half8 a1 = *(const half8*)(A + (size_t)(c0 + 16 + row) * KDIM + kk + kgrp);
        half8 b0 = *(const half8*)(B + (size_t)(j0 +      row) * KDIM + kk + kgrp);
        half8 b1 = *(const half8*)(B + (size_t)(j0 + 16 + row) * KDIM + kk + kgrp);
        acc[0][0] = __builtin_amdgcn_mfma_f32_16x16x32_f16(a0, b0, acc[0][0], 0, 0, 0);
        acc[0][1] = __builtin_amdgcn_mfma_f32_16x16x32_f16(a0, b1, acc[0][1], 0, 0, 0);
        acc[1][0] = __builtin_amdgcn_mfma_f32_16x16x32_f16(a1, b0, acc[1][0], 0, 0, 0);
        acc[1][1] = __builtin_amdgcn_mfma_f32_16x16x32_f16(a1, b1, acc[1][1], 0, 0, 0);
    }
    // C/D layout (verified m89): col = lane&15, row = (lane>>4)*4 + r
    int drow = (lane >> 4) * 4;
    int dcol = lane & 15;
    #pragma unroll
    for (int m = 0; m < 2; m++)
        #pragma unroll
        for (int n = 0; n < 2; n++)
            #pragma unroll
            for (int r = 0; r < 4; r++)
                S[(size_t)(c0 + m * 16 + drow + r) * CP + j0 + n * 16 + dcol] = acc[m][n][r];
}

// One wave per sample: nll_i = LSE_j(y_s[i,j] + h*S[y_i,j]) - value at j=y_i.
// (per-row constant term2 cancels in the LSE difference)
__global__ __launch_bounds__(256) void row_nll_kernel(const float* __restrict__ y_s,
                                                      const float* __restrict__ S,
                                                      const int* __restrict__ labels,
                                                      const float* __restrict__ ratio,
                                                      const float* __restrict__ weights,
                                                      float* __restrict__ acc) {
    int lane = threadIdx.x & 63;
    int i = blockIdx.x * 4 + (threadIdx.x >> 6);
    if (i >= N_SAMP) return;
    int y = labels[i];
    float h = 0.5f * ratio[0];
    const float* ys_row = y_s + (size_t)i * C_CLS;
    const float* s_row  = S   + (size_t)y * CP;

    float v[16];
    float m = -INFINITY, target = -INFINITY;
    #pragma unroll
    for (int k = 0; k < 16; k++) {
        int j = lane + 64 * k;
        float val = -INFINITY;
        if (j < C_CLS) {
            val = ys_row[j] + h * s_row[j];
            if (j == y) target = val;
        }
        v[k] = val;
        m = fmaxf(m, val);
    }
    #pragma unroll
    for (int off = 32; off; off >>= 1) m = fmaxf(m, __shfl_xor(m, off));
    float s = 0.f;
    #pragma unroll
    for (int k = 0; k < 16; k++) s += __expf(v[k] - m);  // exp(-inf)=0 for padding
    #pragma unroll
    for (int off = 32; off; off >>= 1) s += __shfl_xor(s, off);
    #pragma unroll
    for (int off = 32; off; off >>= 1) target = fmaxf(target, __shfl_xor(target, off));

    if (lane == 0) {
        float nll = (m + logf(s)) - target;
        float wgt = weights[y];
        atomicAdd(&acc[0], wgt * nll);
        atomicAdd(&acc[1], wgt);
    }
}

__global__ void finalize_kernel(const float* __restrict__ acc, float* __restrict__ out) {
    out[0] = acc[0] / acc[1];
}

extern "C" void kernel_launch(void* const* d_in, const int* in_sizes, int n_in,
                              void* d_out, int out_size, void* d_ws, size_t ws_size,
                              hipStream_t stream) {
    const float* fc      = (const float*)d_in[0];
    // d_in[1] = features_source (unused by reference)
    const float* y_s     = (const float*)d_in[2];
    const int*   labels  = (const int*)d_in[3];
    const float* ratio   = (const float*)d_in[4];
    const float* weights = (const float*)d_in[5];
    const float* cv      = (const float*)d_in[6];

    char* ws = (char*)d_ws;
    _Float16* Abuf = (_Float16*)ws;                                   // 8 MB
    _Float16* Bbuf = (_Float16*)(ws + (size_t)CP * KDIM * 2);         // 8 MB
    float*    S    = (float*)   (ws + (size_t)CP * KDIM * 4);         // 4 MB
    float*    acc  = (float*)   (ws + (size_t)CP * KDIM * 4 + (size_t)CP * CP * 4);

    hipMemsetAsync(acc, 0, 2 * sizeof(float), stream);
    prep_kernel<<<(CP * KDIM) / 256, 256, 0, stream>>>(fc, cv, Abuf, Bbuf);
    gemm_kernel<<<dim3(CP / 64, CP / 64), 256, 0, stream>>>(Abuf, Bbuf, S);
    row_nll_kernel<<<N_SAMP / 4, 256, 0, stream>>>(y_s, S, labels, ratio, weights, acc);
    finalize_kernel<<<1, 1, 0, stream>>>(acc, (float*)d_out);
}

// Round 2
// 90.484 us; speedup vs baseline: 3.2730x; 3.2730x over previous
//
#include <hip/hip_runtime.h>
#include <hip/hip_bf16.h>
#include <hip/hip_fp16.h>

#define N_SAMP 8192
#define C_CLS  1000
#define A_DIM  2048
#define KDIM   4096   // 2*A_DIM (term1 | term3 folded)
#define CP     1024   // padded C
#define SPLITK 4
#define KSLICE (KDIM / SPLITK)

typedef _Float16 half8 __attribute__((ext_vector_type(8)));
typedef float    f32x4 __attribute__((ext_vector_type(4)));

// Build A' = [cv | -2*fc*cv], B' = [fc^2 | fc] as f16, zero-padded to CP rows.
__global__ __launch_bounds__(256) void prep_kernel(const float* __restrict__ fc,
                                                   const float* __restrict__ cv,
                                                   _Float16* __restrict__ Abuf,
                                                   _Float16* __restrict__ Bbuf) {
    int idx = blockIdx.x * 256 + threadIdx.x;   // over CP*KDIM
    int c = idx >> 12;          // KDIM = 4096
    int k = idx & (KDIM - 1);
    float a = 0.f, b = 0.f;
    if (c < C_CLS) {
        int kk = (k < A_DIM) ? k : (k - A_DIM);
        float cvv = cv[c * A_DIM + kk];
        float f   = fc[c * A_DIM + kk];
        if (k < A_DIM) { a = cvv;            b = f * f; }
        else           { a = -2.f * f * cvv; b = f;     }
    }
    Abuf[idx] = (_Float16)a;
    Bbuf[idx] = (_Float16)b;
}

// Spart[z] = A'[:, zK:(z+1)K] * B'[:, zK:(z+1)K]^T   64x64 tile, 4 waves of 32x32.
__global__ __launch_bounds__(256) void gemm_kernel(const _Float16* __restrict__ A,
                                                   const _Float16* __restrict__ B,
                                                   float* __restrict__ Spart) {
    int lane = threadIdx.x & 63;
    int w    = threadIdx.x >> 6;        // 0..3
    int wr   = w >> 1, wc = w & 1;
    int c0 = blockIdx.y * 64 + wr * 32;
    int j0 = blockIdx.x * 64 + wc * 32;
    int z  = blockIdx.z;
    int row  = lane & 15;
    int kgrp = (lane >> 4) * 8;

    float* Sp = Spart + (size_t)z * CP * CP;
    int k0 = z * KSLICE;

    f32x4 acc[2][2] = {};
    for (int kk = k0; kk < k0 + KSLICE; kk += 32) {
        half8 a0 = *(const half8*)(A + (size_t)(c0 +      row) * KDIM + kk + kgrp);
        half8 a1 = *(const half8*)(A + (size_t)(c0 + 16 + row) * KDIM + kk + kgrp);
        half8 b0 = *(const half8*)(B + (size_t)(j0 +      row) * KDIM + kk + kgrp);
        half8 b1 = *(const half8*)(B + (size_t)(j0 + 16 + row) * KDIM + kk + kgrp);
        acc[0][0] = __builtin_amdgcn_mfma_f32_16x16x32_f16(a0, b0, acc[0][0], 0, 0, 0);
        acc[0][1] = __builtin_amdgcn_mfma_f32_16x16x32_f16(a0, b1, acc[0][1], 0, 0, 0);
        acc[1][0] = __builtin_amdgcn_mfma_f32_16x16x32_f16(a1, b0, acc[1][0], 0, 0, 0);
        acc[1][1] = __builtin_amdgcn_mfma_f32_16x16x32_f16(a1, b1, acc[1][1], 0, 0, 0);
    }
    // C/D layout (verified m89): col = lane&15, row = (lane>>4)*4 + r
    int drow = (lane >> 4) * 4;
    int dcol = lane & 15;
    #pragma unroll
    for (int m = 0; m < 2; m++)
        #pragma unroll
        for (int n = 0; n < 2; n++)
            #pragma unroll
            for (int r = 0; r < 4; r++)
                Sp[(size_t)(c0 + m * 16 + drow + r) * CP + j0 + n * 16 + dcol] = acc[m][n][r];
}

// S = sum_z Spart[z]
__global__ __launch_bounds__(256) void ksum_kernel(const float* __restrict__ Spart,
                                                   float* __restrict__ S) {
    int idx = blockIdx.x * 256 + threadIdx.x;   // over CP*CP/4 float4s
    f32x4 v = ((const f32x4*)Spart)[idx];
    #pragma unroll
    for (int z = 1; z < SPLITK; z++)
        v += ((const f32x4*)(Spart + (size_t)z * CP * CP))[idx];
    ((f32x4*)S)[idx] = v;
}

// One wave per sample: nll_i = LSE_j(y_s[i,j] + h*S[y_i,j]) - value at j=y_i.
// Per-row constant term2 cancels in the LSE difference. No global atomics:
// block partials -> finalize kernel.
__global__ __launch_bounds__(256) void row_nll_kernel(const float* __restrict__ y_s,
                                                      const float* __restrict__ S,
                                                      const int* __restrict__ labels,
                                                      const float* __restrict__ ratio,
                                                      const float* __restrict__ weights,
                                                      float* __restrict__ partial) {
    int lane = threadIdx.x & 63;
    int w = threadIdx.x >> 6;
    int i = blockIdx.x * 4 + w;
    int y = labels[i];
    float h = 0.5f * ratio[0];
    const float* ys_row = y_s + (size_t)i * C_CLS;
    const float* s_row  = S   + (size_t)y * CP;

    float v[16];
    float m = -INFINITY, target = -INFINITY;
    #pragma unroll
    for (int k = 0; k < 4; k++) {
        int j = lane * 4 + 256 * k;          // multiple of 4; j<1000 => j+3<=999
        if (j < C_CLS) {
            f32x4 ys = *(const f32x4*)(ys_row + j);
            f32x4 sv = *(const f32x4*)(s_row + j);
            #pragma unroll
            for (int t = 0; t < 4; t++) {
                float val = ys[t] + h * sv[t];
                v[k * 4 + t] = val;
                m = fmaxf(m, val);
                if (j + t == y) target = val;
            }
        } else {
            #pragma unroll
            for (int t = 0; t < 4; t++) v[k * 4 + t] = -INFINITY;
        }
    }
    #pragma unroll
    for (int off = 32; off; off >>= 1) m = fmaxf(m, __shfl_xor(m, off));
    float s = 0.f;
    #pragma unroll
    for (int k = 0; k < 16; k++) s += __expf(v[k] - m);  // exp(-inf)=0 for padding
    #pragma unroll
    for (int off = 32; off; off >>= 1) s += __shfl_xor(s, off);
    #pragma unroll
    for (int off = 32; off; off >>= 1) target = fmaxf(target, __shfl_xor(target, off));

    __shared__ float swn[4], sww[4];
    if (lane == 0) {
        float wgt = weights[y];
        swn[w] = wgt * ((m + logf(s)) - target);
        sww[w] = wgt;
    }
    __syncthreads();
    if (threadIdx.x == 0) {
        partial[2 * blockIdx.x]     = swn[0] + swn[1] + swn[2] + swn[3];
        partial[2 * blockIdx.x + 1] = sww[0] + sww[1] + sww[2] + sww[3];
    }
}

#define NBLK_NLL (N_SAMP / 4)

__global__ __launch_bounds__(256) void finalize_kernel(const float* __restrict__ partial,
                                                       float* __restrict__ out) {
    float a = 0.f, b = 0.f;
    for (int i = threadIdx.x; i < NBLK_NLL; i += 256) {
        a += partial[2 * i];
        b += partial[2 * i + 1];
    }
    #pragma unroll
    for (int off = 32; off; off >>= 1) { a += __shfl_xor(a, off); b += __shfl_xor(b, off); }
    __shared__ float wa[4], wb[4];
    int w = threadIdx.x >> 6;
    if ((threadIdx.x & 63) == 0) { wa[w] = a; wb[w] = b; }
    __syncthreads();
    if (threadIdx.x == 0)
        out[0] = (wa[0] + wa[1] + wa[2] + wa[3]) / (wb[0] + wb[1] + wb[2] + wb[3]);
}

extern "C" void kernel_launch(void* const* d_in, const int* in_sizes, int n_in,
                              void* d_out, int out_size, void* d_ws, size_t ws_size,
                              hipStream_t stream) {
    const float* fc      = (const float*)d_in[0];
    // d_in[1] = features_source (unused by reference)
    const float* y_s     = (const float*)d_in[2];
    const int*   labels  = (const int*)d_in[3];
    const float* ratio   = (const float*)d_in[4];
    const float* weights = (const float*)d_in[5];
    const float* cv      = (const float*)d_in[6];

    char* ws = (char*)d_ws;
    _Float16* Abuf  = (_Float16*)ws;                                  // [0, 8 MB)
    _Float16* Bbuf  = (_Float16*)(ws + (size_t)8 * 1024 * 1024);      // [8, 16 MB)
    float*    Spart = (float*)   (ws + (size_t)16 * 1024 * 1024);     // [16, 32 MB)
    float*    S     = (float*)ws;                                     // reuse Abuf region after gemm
    float*    part  = (float*)   (ws + (size_t)32 * 1024 * 1024);     // 16 KB

    prep_kernel<<<(CP * KDIM) / 256, 256, 0, stream>>>(fc, cv, Abuf, Bbuf);
    gemm_kernel<<<dim3(CP / 64, CP / 64, SPLITK), 256, 0, stream>>>(Abuf, Bbuf, Spart);
    ksum_kernel<<<(CP * CP / 4) / 256, 256, 0, stream>>>(Spart, S);
    row_nll_kernel<<<NBLK_NLL, 256, 0, stream>>>(y_s, S, labels, ratio, weights, part);
    finalize_kernel<<<1, 256, 0, stream>>>(part, (float*)d_out);
}

// Round 3
// 77.012 us; speedup vs baseline: 3.8456x; 1.1749x over previous
//
#include <hip/hip_runtime.h>
#include <hip/hip_bf16.h>
#include <hip/hip_fp16.h>

#define N_SAMP 8192
#define C_CLS  1000
#define A_DIM  2048
#define KDIM   4096   // 2*A_DIM (term1 | term3 folded)
#define CP     1024   // padded C

typedef _Float16 half8 __attribute__((ext_vector_type(8)));
typedef _Float16 half4 __attribute__((ext_vector_type(4)));
typedef float    f32x4 __attribute__((ext_vector_type(4)));

// Build A' = [cv | -2*fc*cv], B' = [fc^2 | fc] as f16. Vectorized: one f32x4
// read of fc/cv each, four half4 writes. Rows 1000..1023 zeroed by memsetAsync.
__global__ __launch_bounds__(256) void prep_kernel(const float* __restrict__ fc,
                                                   const float* __restrict__ cv,
                                                   _Float16* __restrict__ Ab,
                                                   _Float16* __restrict__ Bb) {
    int i4 = blockIdx.x * 256 + threadIdx.x;   // over C_CLS*A_DIM/4
    int c  = i4 >> 9;                          // A_DIM/4 = 512
    int k4 = i4 & 511;
    f32x4 f = ((const f32x4*)fc)[i4];
    f32x4 v = ((const f32x4*)cv)[i4];
    half4 aL, aR, bL, bR;
    #pragma unroll
    for (int t = 0; t < 4; t++) {
        aL[t] = (_Float16)v[t];
        aR[t] = (_Float16)(-2.f * f[t] * v[t]);
        bL[t] = (_Float16)(f[t] * f[t]);
        bR[t] = (_Float16)f[t];
    }
    size_t ro = (size_t)c * KDIM + k4 * 4;
    *(half4*)(Ab + ro)         = aL;
    *(half4*)(Ab + ro + A_DIM) = aR;
    *(half4*)(Bb + ro)         = bL;
    *(half4*)(Bb + ro + A_DIM) = bR;
}

// Spart[z] = A'[:,zKS:(z+1)KS] * B'[:,...]^T.  m97 structure: 128x128 tile,
// BK=32, global_load_lds(16B) staging, double-buffered LDS, 4 waves x 64x64.
// Granule XOR-swizzle (g ^ (row>>1)&3) applied on the GLOBAL source address
// (LDS written linearly by global_load_lds) and on the ds_read address.
// blockIdx.x = z so each XCD (linear%8) owns one K-slice: 2MB, L2-resident.
template<int Z>
__global__ __launch_bounds__(256) void gemm_kernel(const _Float16* __restrict__ A,
                                                   const _Float16* __restrict__ B,
                                                   float* __restrict__ Spart) {
    constexpr int KS = KDIM / Z;
    constexpr int NT = KS / 32;
    __shared__ _Float16 As[2][128][32];
    __shared__ _Float16 Bs[2][128][32];

    int z  = blockIdx.x;
    int tj = blockIdx.y;      // col tile
    int tc = blockIdx.z;      // row tile
    int tid  = threadIdx.x;
    int lane = tid & 63;
    int w    = tid >> 6;
    int wr = w >> 1, wc = w & 1;
    int k0 = z * KS;

    const size_t arow0 = (size_t)tc * 128;
    const size_t brow0 = (size_t)tj * 128;

#define STAGE(p, kcur)                                                                  \
    {                                                                                   \
        _Pragma("unroll")                                                               \
        for (int issue = 0; issue < 2; ++issue) {                                       \
            int t16 = issue * 256 + tid;                                                \
            int row = t16 >> 2, gp = t16 & 3;                                           \
            int gs  = gp ^ ((row >> 1) & 3);                                            \
            const _Float16* ga = A + (arow0 + row) * KDIM + (kcur) + gs * 8;            \
            const _Float16* gb = B + (brow0 + row) * KDIM + (kcur) + gs * 8;            \
            char* la = (char*)&As[p][0][0] + (issue * 256 + w * 64) * 16;               \
            char* lb = (char*)&Bs[p][0][0] + (issue * 256 + w * 64) * 16;               \
            __builtin_amdgcn_global_load_lds(                                           \
                (const __attribute__((address_space(1))) void*)ga,                      \
                (__attribute__((address_space(3))) void*)la, 16, 0, 0);                 \
            __builtin_amdgcn_global_load_lds(                                           \
                (const __attribute__((address_space(1))) void*)gb,                      \
                (__attribute__((address_space(3))) void*)lb, 16, 0, 0);                 \
        }                                                                               \
    }

    f32x4 acc[4][4] = {};
    int r16 = lane & 15;
    int g   = lane >> 4;

    STAGE(0, k0);
    __syncthreads();
    for (int t = 0; t < NT; ++t) {
        int cur = t & 1;
        if (t + 1 < NT) STAGE(cur ^ 1, k0 + (t + 1) * 32);
        half8 af[4], bf[4];
        #pragma unroll
        for (int m = 0; m < 4; m++) {
            int row = wr * 64 + m * 16 + r16;
            af[m] = *(const half8*)&As[cur][row][(g ^ ((row >> 1) & 3)) * 8];
        }
        #pragma unroll
        for (int n = 0; n < 4; n++) {
            int row = wc * 64 + n * 16 + r16;
            bf[n] = *(const half8*)&Bs[cur][row][(g ^ ((row >> 1) & 3)) * 8];
        }
        #pragma unroll
        for (int m = 0; m < 4; m++)
            #pragma unroll
            for (int n = 0; n < 4; n++)
                acc[m][n] = __builtin_amdgcn_mfma_f32_16x16x32_f16(af[m], bf[n], acc[m][n], 0, 0, 0);
        __syncthreads();
    }
#undef STAGE

    // C/D layout (verified m89): col = lane&15, row = (lane>>4)*4 + r
    float* Sp = Spart + (size_t)z * CP * CP;
    int drow = (lane >> 4) * 4;
    int dcol = lane & 15;
    #pragma unroll
    for (int m = 0; m < 4; m++)
        #pragma unroll
        for (int n = 0; n < 4; n++)
            #pragma unroll
            for (int r = 0; r < 4; r++)
                Sp[(size_t)(tc * 128 + wr * 64 + m * 16 + drow + r) * CP
                   + tj * 128 + wc * 64 + n * 16 + dcol] = acc[m][n][r];
}

// One wave per sample: nll_i = LSE_j(y_s[i,j] + h*sum_z Spart[z][y_i,j]) - at j=y_i.
// term2 (per-row constant) cancels in the LSE difference. ksum fused here:
// the Z partial rows are L2-resident. Block partials, no global atomics.
template<int Z>
__global__ __launch_bounds__(256) void row_nll_kernel(const float* __restrict__ y_s,
                                                      const float* __restrict__ Spart,
                                                      const int* __restrict__ labels,
                                                      const float* __restrict__ ratio,
                                                      const float* __restrict__ weights,
                                                      float* __restrict__ partial) {
    int lane = threadIdx.x & 63;
    int w = threadIdx.x >> 6;
    int i = blockIdx.x * 4 + w;
    int y = labels[i];
    float h = 0.5f * ratio[0];
    const float* ys_row = y_s   + (size_t)i * C_CLS;
    const float* s_row  = Spart + (size_t)y * CP;

    float v[16];
    float m = -INFINITY, target = -INFINITY;
    #pragma unroll
    for (int k = 0; k < 4; k++) {
        int j = lane * 4 + 256 * k;          // multiple of 4; j<1000 => j+3<=999
        if (j < C_CLS) {
            f32x4 ys = *(const f32x4*)(ys_row + j);
            f32x4 sv = *(const f32x4*)(s_row + j);
            #pragma unroll
            for (int z = 1; z < Z; z++)
                sv += *(const f32x4*)(s_row + (size_t)z * CP * CP + j);
            #pragma unroll
            for (int t = 0; t < 4; t++) {
                float val = ys[t] + h * sv[t];
                v[k * 4 + t] = val;
                m = fmaxf(m, val);
                if (j + t == y) target = val;
            }
        } else {
            #pragma unroll
            for (int t = 0; t < 4; t++) v[k * 4 + t] = -INFINITY;
        }
    }
    #pragma unroll
    for (int off = 32; off; off >>= 1) m = fmaxf(m, __shfl_xor(m, off));
    float s = 0.f;
    #pragma unroll
    for (int k = 0; k < 16; k++) s += __expf(v[k] - m);  // exp(-inf)=0 for padding
    #pragma unroll
    for (int off = 32; off; off >>= 1) s += __shfl_xor(s, off);
    #pragma unroll
    for (int off = 32; off; off >>= 1) target = fmaxf(target, __shfl_xor(target, off));

    __shared__ float swn[4], sww[4];
    if (lane == 0) {
        float wgt = weights[y];
        swn[w] = wgt * ((m + logf(s)) - target);
        sww[w] = wgt;
    }
    __syncthreads();
    if (threadIdx.x == 0) {
        partial[2 * blockIdx.x]     = swn[0] + swn[1] + swn[2] + swn[3];
        partial[2 * blockIdx.x + 1] = sww[0] + sww[1] + sww[2] + sww[3];
    }
}

#define NBLK_NLL (N_SAMP / 4)

__global__ __launch_bounds__(256) void finalize_kernel(const float* __restrict__ partial,
                                                       float* __restrict__ out) {
    float a = 0.f, b = 0.f;
    for (int i = threadIdx.x; i < NBLK_NLL; i += 256) {
        a += partial[2 * i];
        b += partial[2 * i + 1];
    }
    #pragma unroll
    for (int off = 32; off; off >>= 1) { a += __shfl_xor(a, off); b += __shfl_xor(b, off); }
    __shared__ float wa[4], wb[4];
    int w = threadIdx.x >> 6;
    if ((threadIdx.x & 63) == 0) { wa[w] = a; wb[w] = b; }
    __syncthreads();
    if (threadIdx.x == 0)
        out[0] = (wa[0] + wa[1] + wa[2] + wa[3]) / (wb[0] + wb[1] + wb[2] + wb[3]);
}

extern "C" void kernel_launch(void* const* d_in, const int* in_sizes, int n_in,
                              void* d_out, int out_size, void* d_ws, size_t ws_size,
                              hipStream_t stream) {
    const float* fc      = (const float*)d_in[0];
    // d_in[1] = features_source (unused by reference)
    const float* y_s     = (const float*)d_in[2];
    const int*   labels  = (const int*)d_in[3];
    const float* ratio   = (const float*)d_in[4];
    const float* weights = (const float*)d_in[5];
    const float* cv      = (const float*)d_in[6];

    char* ws = (char*)d_ws;
    _Float16* Abuf  = (_Float16*)ws;                                  // [0, 8 MB)
    _Float16* Bbuf  = (_Float16*)(ws + (size_t)8 * 1024 * 1024);      // [8, 16 MB)
    float*    Spart = (float*)   (ws + (size_t)16 * 1024 * 1024);     // Z * 4 MB

    const bool big = ws_size >= ((size_t)48 * 1024 * 1024 + 65536);
    const int  Z   = big ? 8 : 4;
    float* part = (float*)(ws + (size_t)(16 + 4 * Z) * 1024 * 1024);  // 16 KB

    // zero f16 pad rows 1000..1023 of A'/B'
    size_t padoff = (size_t)C_CLS * KDIM * 2, padlen = (size_t)(CP - C_CLS) * KDIM * 2;
    hipMemsetAsync((char*)Abuf + padoff, 0, padlen, stream);
    hipMemsetAsync((char*)Bbuf + padoff, 0, padlen, stream);

    prep_kernel<<<(C_CLS * A_DIM / 4) / 256, 256, 0, stream>>>(fc, cv, Abuf, Bbuf);
    if (big) {
        gemm_kernel<8><<<dim3(8, 8, 8), 256, 0, stream>>>(Abuf, Bbuf, Spart);
        row_nll_kernel<8><<<NBLK_NLL, 256, 0, stream>>>(y_s, Spart, labels, ratio, weights, part);
    } else {
        gemm_kernel<4><<<dim3(4, 8, 8), 256, 0, stream>>>(Abuf, Bbuf, Spart);
        row_nll_kernel<4><<<NBLK_NLL, 256, 0, stream>>>(y_s, Spart, labels, ratio, weights, part);
    }
    finalize_kernel<<<1, 256, 0, stream>>>(part, (float*)d_out);
}

// Round 4
// 54.115 us; speedup vs baseline: 5.4727x; 1.4231x over previous
//
#include <hip/hip_runtime.h>
#include <hip/hip_bf16.h>
#include <hip/hip_fp16.h>

#define N_SAMP 8192
#define C_CLS  1000
#define A_DIM  2048
#define KDIM   4096   // 2*A_DIM (term1 | term3 folded)
#define CP     1024   // padded C

typedef _Float16 half8 __attribute__((ext_vector_type(8)));
typedef _Float16 half4 __attribute__((ext_vector_type(4)));
typedef float    f32x4 __attribute__((ext_vector_type(4)));

// Build A' = [cv | -2*fc*cv], B' = [fc^2 | fc] as f16. Vectorized: one f32x4
// read of fc/cv each, four half4 writes. Rows 1000..1023 zeroed by memsetAsync.
__global__ __launch_bounds__(256) void prep_kernel(const float* __restrict__ fc,
                                                   const float* __restrict__ cv,
                                                   _Float16* __restrict__ Ab,
                                                   _Float16* __restrict__ Bb) {
    int i4 = blockIdx.x * 256 + threadIdx.x;   // over C_CLS*A_DIM/4
    int c  = i4 >> 9;                          // A_DIM/4 = 512
    int k4 = i4 & 511;
    f32x4 f = ((const f32x4*)fc)[i4];
    f32x4 v = ((const f32x4*)cv)[i4];
    half4 aL, aR, bL, bR;
    #pragma unroll
    for (int t = 0; t < 4; t++) {
        aL[t] = (_Float16)v[t];
        aR[t] = (_Float16)(-2.f * f[t] * v[t]);
        bL[t] = (_Float16)(f[t] * f[t]);
        bR[t] = (_Float16)f[t];
    }
    size_t ro = (size_t)c * KDIM + k4 * 4;
    *(half4*)(Ab + ro)         = aL;
    *(half4*)(Ab + ro + A_DIM) = aR;
    *(half4*)(Bb + ro)         = bL;
    *(half4*)(Bb + ro + A_DIM) = bR;
}

// Spart[z] = A'[:,zKS:(z+1)KS] * B'[:,...]^T.  m97 structure: 128x128 tile,
// BK=32, global_load_lds(16B) staging, double-buffered LDS, 4 waves x 64x64.
// Granule XOR-swizzle (g ^ (row>>1)&3) applied on the GLOBAL source address
// (LDS written linearly by global_load_lds) and on the ds_read address.
// blockIdx.x = z so each XCD (linear%8) owns one K-slice: 2MB, L2-resident.
template<int Z>
__global__ __launch_bounds__(256) void gemm_kernel(const _Float16* __restrict__ A,
                                                   const _Float16* __restrict__ B,
                                                   float* __restrict__ Spart) {
    constexpr int KS = KDIM / Z;
    constexpr int NT = KS / 32;
    __shared__ _Float16 As[2][128][32];
    __shared__ _Float16 Bs[2][128][32];

    int z  = blockIdx.x;
    int tj = blockIdx.y;      // col tile
    int tc = blockIdx.z;      // row tile
    int tid  = threadIdx.x;
    int lane = tid & 63;
    int w    = tid >> 6;
    int wr = w >> 1, wc = w & 1;
    int k0 = z * KS;

    const size_t arow0 = (size_t)tc * 128;
    const size_t brow0 = (size_t)tj * 128;

#define STAGE(p, kcur)                                                                  \
    {                                                                                   \
        _Pragma("unroll")                                                               \
        for (int issue = 0; issue < 2; ++issue) {                                       \
            int t16 = issue * 256 + tid;                                                \
            int row = t16 >> 2, gp = t16 & 3;                                           \
            int gs  = gp ^ ((row >> 1) & 3);                                            \
            const _Float16* ga = A + (arow0 + row) * KDIM + (kcur) + gs * 8;            \
            const _Float16* gb = B + (brow0 + row) * KDIM + (kcur) + gs * 8;            \
            char* la = (char*)&As[p][0][0] + (issue * 256 + w * 64) * 16;               \
            char* lb = (char*)&Bs[p][0][0] + (issue * 256 + w * 64) * 16;               \
            __builtin_amdgcn_global_load_lds(                                           \
                (const __attribute__((address_space(1))) void*)ga,                      \
                (__attribute__((address_space(3))) void*)la, 16, 0, 0);                 \
            __builtin_amdgcn_global_load_lds(                                           \
                (const __attribute__((address_space(1))) void*)gb,                      \
                (__attribute__((address_space(3))) void*)lb, 16, 0, 0);                 \
        }                                                                               \
    }

    f32x4 acc[4][4] = {};
    int r16 = lane & 15;
    int g   = lane >> 4;

    STAGE(0, k0);
    __syncthreads();
    for (int t = 0; t < NT; ++t) {
        int cur = t & 1;
        if (t + 1 < NT) STAGE(cur ^ 1, k0 + (t + 1) * 32);
        half8 af[4], bf[4];
        #pragma unroll
        for (int m = 0; m < 4; m++) {
            int row = wr * 64 + m * 16 + r16;
            af[m] = *(const half8*)&As[cur][row][(g ^ ((row >> 1) & 3)) * 8];
        }
        #pragma unroll
        for (int n = 0; n < 4; n++) {
            int row = wc * 64 + n * 16 + r16;
            bf[n] = *(const half8*)&Bs[cur][row][(g ^ ((row >> 1) & 3)) * 8];
        }
        #pragma unroll
        for (int m = 0; m < 4; m++)
            #pragma unroll
            for (int n = 0; n < 4; n++)
                acc[m][n] = __builtin_amdgcn_mfma_f32_16x16x32_f16(af[m], bf[n], acc[m][n], 0, 0, 0);
        __syncthreads();
    }
#undef STAGE

    // C/D layout (verified m89): col = lane&15, row = (lane>>4)*4 + r
    float* Sp = Spart + (size_t)z * CP * CP;
    int drow = (lane >> 4) * 4;
    int dcol = lane & 15;
    #pragma unroll
    for (int m = 0; m < 4; m++)
        #pragma unroll
        for (int n = 0; n < 4; n++)
            #pragma unroll
            for (int r = 0; r < 4; r++)
                Sp[(size_t)(tc * 128 + wr * 64 + m * 16 + drow + r) * CP
                   + tj * 128 + wc * 64 + n * 16 + dcol] = acc[m][n][r];
}

// S = sum_z Spart[z].  Streaming 36 MB; compact 4 MB S then serves row_nll's
// label-random row reads from L2/L3 (round-3 lesson: fusing this into
// row_nll re-fetched ~100 MB from HBM).
template<int Z>
__global__ __launch_bounds__(256) void ksum_kernel(const float* __restrict__ Spart,
                                                   float* __restrict__ S) {
    int idx = blockIdx.x * 256 + threadIdx.x;   // over CP*CP/4 float4s
    f32x4 v = ((const f32x4*)Spart)[idx];
    #pragma unroll
    for (int z = 1; z < Z; z++)
        v += ((const f32x4*)(Spart + (size_t)z * CP * CP))[idx];
    ((f32x4*)S)[idx] = v;
}

// One wave per sample: nll_i = LSE_j(y_s[i,j] + h*S[y_i,j]) - value at j=y_i.
// term2 (per-row constant) cancels in the LSE difference. Block partials,
// no global atomics.
__global__ __launch_bounds__(256) void row_nll_kernel(const float* __restrict__ y_s,
                                                      const float* __restrict__ S,
                                                      const int* __restrict__ labels,
                                                      const float* __restrict__ ratio,
                                                      const float* __restrict__ weights,
                                                      float* __restrict__ partial) {
    int lane = threadIdx.x & 63;
    int w = threadIdx.x >> 6;
    int i = blockIdx.x * 4 + w;
    int y = labels[i];
    float h = 0.5f * ratio[0];
    const float* ys_row = y_s + (size_t)i * C_CLS;
    const float* s_row  = S   + (size_t)y * CP;

    float v[16];
    float m = -INFINITY, target = -INFINITY;
    #pragma unroll
    for (int k = 0; k < 4; k++) {
        int j = lane * 4 + 256 * k;          // multiple of 4; j<1000 => j+3<=999
        if (j < C_CLS) {
            f32x4 ys = *(const f32x4*)(ys_row + j);
            f32x4 sv = *(const f32x4*)(s_row + j);
            #pragma unroll
            for (int t = 0; t < 4; t++) {
                float val = ys[t] + h * sv[t];
                v[k * 4 + t] = val;
                m = fmaxf(m, val);
                if (j + t == y) target = val;
            }
        } else {
            #pragma unroll
            for (int t = 0; t < 4; t++) v[k * 4 + t] = -INFINITY;
        }
    }
    #pragma unroll
    for (int off = 32; off; off >>= 1) m = fmaxf(m, __shfl_xor(m, off));
    float s = 0.f;
    #pragma unroll
    for (int k = 0; k < 16; k++) s += __expf(v[k] - m);  // exp(-inf)=0 for padding
    #pragma unroll
    for (int off = 32; off; off >>= 1) s += __shfl_xor(s, off);
    #pragma unroll
    for (int off = 32; off; off >>= 1) target = fmaxf(target, __shfl_xor(target, off));

    __shared__ float swn[4], sww[4];
    if (lane == 0) {
        float wgt = weights[y];
        swn[w] = wgt * ((m + logf(s)) - target);
        sww[w] = wgt;
    }
    __syncthreads();
    if (threadIdx.x == 0) {
        partial[2 * blockIdx.x]     = swn[0] + swn[1] + swn[2] + swn[3];
        partial[2 * blockIdx.x + 1] = sww[0] + sww[1] + sww[2] + sww[3];
    }
}

#define NBLK_NLL (N_SAMP / 4)

__global__ __launch_bounds__(256) void finalize_kernel(const float* __restrict__ partial,
                                                       float* __restrict__ out) {
    float a = 0.f, b = 0.f;
    for (int i = threadIdx.x; i < NBLK_NLL; i += 256) {
        a += partial[2 * i];
        b += partial[2 * i + 1];
    }
    #pragma unroll
    for (int off = 32; off; off >>= 1) { a += __shfl_xor(a, off); b += __shfl_xor(b, off); }
    __shared__ float wa[4], wb[4];
    int w = threadIdx.x >> 6;
    if ((threadIdx.x & 63) == 0) { wa[w] = a; wb[w] = b; }
    __syncthreads();
    if (threadIdx.x == 0)
        out[0] = (wa[0] + wa[1] + wa[2] + wa[3]) / (wb[0] + wb[1] + wb[2] + wb[3]);
}

extern "C" void kernel_launch(void* const* d_in, const int* in_sizes, int n_in,
                              void* d_out, int out_size, void* d_ws, size_t ws_size,
                              hipStream_t stream) {
    const float* fc      = (const float*)d_in[0];
    // d_in[1] = features_source (unused by reference)
    const float* y_s     = (const float*)d_in[2];
    const int*   labels  = (const int*)d_in[3];
    const float* ratio   = (const float*)d_in[4];
    const float* weights = (const float*)d_in[5];
    const float* cv      = (const float*)d_in[6];

    char* ws = (char*)d_ws;
    _Float16* Abuf  = (_Float16*)ws;                                  // [0, 8 MB)
    _Float16* Bbuf  = (_Float16*)(ws + (size_t)8 * 1024 * 1024);      // [8, 16 MB)
    float*    Spart = (float*)   (ws + (size_t)16 * 1024 * 1024);     // Z * 4 MB
    float*    S     = (float*)ws;   // reuse Abuf region after gemm completes

    const bool big = ws_size >= ((size_t)48 * 1024 * 1024 + 65536);
    const int  Z   = big ? 8 : 4;
    float* part = (float*)(ws + (size_t)(16 + 4 * Z) * 1024 * 1024);  // 16 KB

    // zero f16 pad rows 1000..1023 of A'/B'
    size_t padoff = (size_t)C_CLS * KDIM * 2, padlen = (size_t)(CP - C_CLS) * KDIM * 2;
    hipMemsetAsync((char*)Abuf + padoff, 0, padlen, stream);
    hipMemsetAsync((char*)Bbuf + padoff, 0, padlen, stream);

    prep_kernel<<<(C_CLS * A_DIM / 4) / 256, 256, 0, stream>>>(fc, cv, Abuf, Bbuf);
    if (big) {
        gemm_kernel<8><<<dim3(8, 8, 8), 256, 0, stream>>>(Abuf, Bbuf, Spart);
        ksum_kernel<8><<<(CP * CP / 4) / 256, 256, 0, stream>>>(Spart, S);
    } else {
        gemm_kernel<4><<<dim3(4, 8, 8), 256, 0, stream>>>(Abuf, Bbuf, Spart);
        ksum_kernel<4><<<(CP * CP / 4) / 256, 256, 0, stream>>>(Spart, S);
    }
    row_nll_kernel<<<NBLK_NLL, 256, 0, stream>>>(y_s, S, labels, ratio, weights, part);
    finalize_kernel<<<1, 256, 0, stream>>>(part, (float*)d_out);
}

// Round 5
// 42.758 us; speedup vs baseline: 6.9263x; 1.2656x over previous
//
#include <hip/hip_runtime.h>
#include <hip/hip_bf16.h>
#include <hip/hip_fp16.h>

#define N_SAMP 8192
#define C_CLS  1000
#define A_DIM  2048
#define KDIM   4096   // 2*A_DIM (term1 | term3 folded)
#define CP     1024   // padded C

typedef _Float16 half8 __attribute__((ext_vector_type(8)));
typedef _Float16 half4 __attribute__((ext_vector_type(4)));
typedef float    f32x4 __attribute__((ext_vector_type(4)));

// Build A' = [cv | -2*fc*cv], B' = [fc^2 | fc] as f16, covering ALL CP rows
// (rows >= C_CLS written as zeros -> no separate memset dispatches).
__global__ __launch_bounds__(256) void prep_kernel(const float* __restrict__ fc,
                                                   const float* __restrict__ cv,
                                                   _Float16* __restrict__ Ab,
                                                   _Float16* __restrict__ Bb) {
    int i4 = blockIdx.x * 256 + threadIdx.x;   // over CP*A_DIM/4
    int c  = i4 >> 9;                          // A_DIM/4 = 512
    int k4 = i4 & 511;
    f32x4 f = {0.f, 0.f, 0.f, 0.f}, v = {0.f, 0.f, 0.f, 0.f};
    if (c < C_CLS) {
        size_t off = (size_t)c * (A_DIM / 4) + k4;
        f = ((const f32x4*)fc)[off];
        v = ((const f32x4*)cv)[off];
    }
    half4 aL, aR, bL, bR;
    #pragma unroll
    for (int t = 0; t < 4; t++) {
        aL[t] = (_Float16)v[t];
        aR[t] = (_Float16)(-2.f * f[t] * v[t]);
        bL[t] = (_Float16)(f[t] * f[t]);
        bR[t] = (_Float16)f[t];
    }
    size_t ro = (size_t)c * KDIM + k4 * 4;
    *(half4*)(Ab + ro)         = aL;
    *(half4*)(Ab + ro + A_DIM) = aR;
    *(half4*)(Bb + ro)         = bL;
    *(half4*)(Bb + ro + A_DIM) = bR;
}

// Spart[z] = A'[:,zKS:(z+1)KS] * B'[:,...]^T.  m97 structure: 128x128 tile,
// BK=32, global_load_lds(16B) staging, double-buffered LDS, 4 waves x 64x64.
// Granule XOR-swizzle (g ^ (row>>1)&3) applied on the GLOBAL source address
// (LDS written linearly by global_load_lds) and on the ds_read address.
// Partials stored as f16 (values O(1); error ~1e-3 << 0.156 threshold).
template<int Z>
__global__ __launch_bounds__(256) void gemm_kernel(const _Float16* __restrict__ A,
                                                   const _Float16* __restrict__ B,
                                                   _Float16* __restrict__ Spart) {
    constexpr int KS = KDIM / Z;
    constexpr int NT = KS / 32;
    __shared__ _Float16 As[2][128][32];
    __shared__ _Float16 Bs[2][128][32];

    int z  = blockIdx.x;
    int tj = blockIdx.y;      // col tile
    int tc = blockIdx.z;      // row tile
    int tid  = threadIdx.x;
    int lane = tid & 63;
    int w    = tid >> 6;
    int wr = w >> 1, wc = w & 1;
    int k0 = z * KS;

    const size_t arow0 = (size_t)tc * 128;
    const size_t brow0 = (size_t)tj * 128;

#define STAGE(p, kcur)                                                                  \
    {                                                                                   \
        _Pragma("unroll")                                                               \
        for (int issue = 0; issue < 2; ++issue) {                                       \
            int t16 = issue * 256 + tid;                                                \
            int row = t16 >> 2, gp = t16 & 3;                                           \
            int gs  = gp ^ ((row >> 1) & 3);                                            \
            const _Float16* ga = A + (arow0 + row) * KDIM + (kcur) + gs * 8;            \
            const _Float16* gb = B + (brow0 + row) * KDIM + (kcur) + gs * 8;            \
            char* la = (char*)&As[p][0][0] + (issue * 256 + w * 64) * 16;               \
            char* lb = (char*)&Bs[p][0][0] + (issue * 256 + w * 64) * 16;               \
            __builtin_amdgcn_global_load_lds(                                           \
                (const __attribute__((address_space(1))) void*)ga,                      \
                (__attribute__((address_space(3))) void*)la, 16, 0, 0);                 \
            __builtin_amdgcn_global_load_lds(                                           \
                (const __attribute__((address_space(1))) void*)gb,                      \
                (__attribute__((address_space(3))) void*)lb, 16, 0, 0);                 \
        }                                                                               \
    }

    f32x4 acc[4][4] = {};
    int r16 = lane & 15;
    int g   = lane >> 4;

    STAGE(0, k0);
    __syncthreads();
    for (int t = 0; t < NT; ++t) {
        int cur = t & 1;
        if (t + 1 < NT) STAGE(cur ^ 1, k0 + (t + 1) * 32);
        half8 af[4], bf[4];
        #pragma unroll
        for (int m = 0; m < 4; m++) {
            int row = wr * 64 + m * 16 + r16;
            af[m] = *(const half8*)&As[cur][row][(g ^ ((row >> 1) & 3)) * 8];
        }
        #pragma unroll
        for (int n = 0; n < 4; n++) {
            int row = wc * 64 + n * 16 + r16;
            bf[n] = *(const half8*)&Bs[cur][row][(g ^ ((row >> 1) & 3)) * 8];
        }
        #pragma unroll
        for (int m = 0; m < 4; m++)
            #pragma unroll
            for (int n = 0; n < 4; n++)
                acc[m][n] = __builtin_amdgcn_mfma_f32_16x16x32_f16(af[m], bf[n], acc[m][n], 0, 0, 0);
        __syncthreads();
    }
#undef STAGE

    // C/D layout (verified m89): col = lane&15, row = (lane>>4)*4 + r
    _Float16* Sp = Spart + (size_t)z * CP * CP;
    int drow = (lane >> 4) * 4;
    int dcol = lane & 15;
    #pragma unroll
    for (int m = 0; m < 4; m++)
        #pragma unroll
        for (int n = 0; n < 4; n++)
            #pragma unroll
            for (int r = 0; r < 4; r++)
                Sp[(size_t)(tc * 128 + wr * 64 + m * 16 + drow + r) * CP
                   + tj * 128 + wc * 64 + n * 16 + dcol] = (_Float16)acc[m][n][r];
}

// S = sum_z Spart[z] (f16 in, f32 accumulate, f16 out).  Compact 2 MB S then
// serves row_nll's label-random row reads from L2/L3 (round-3 lesson: fusing
// this into row_nll re-fetched ~100 MB from HBM).
template<int Z>
__global__ __launch_bounds__(256) void ksum_kernel(const _Float16* __restrict__ Spart,
                                                   _Float16* __restrict__ S) {
    size_t idx = (size_t)blockIdx.x * 256 + threadIdx.x;   // over CP*CP/8 half8s
    float a[8] = {};
    #pragma unroll
    for (int z = 0; z < Z; z++) {
        half8 v = ((const half8*)(Spart + (size_t)z * CP * CP))[idx];
        #pragma unroll
        for (int t = 0; t < 8; t++) a[t] += (float)v[t];
    }
    half8 o;
    #pragma unroll
    for (int t = 0; t < 8; t++) o[t] = (_Float16)a[t];
    ((half8*)S)[idx] = o;
}

// One wave per sample: nll_i = LSE_j(y_s[i,j] + h*S[y_i,j]) - value at j=y_i.
// term2 (per-row constant) cancels in the LSE difference. Block partials,
// no global atomics.
__global__ __launch_bounds__(256) void row_nll_kernel(const float* __restrict__ y_s,
                                                      const _Float16* __restrict__ S,
                                                      const int* __restrict__ labels,
                                                      const float* __restrict__ ratio,
                                                      const float* __restrict__ weights,
                                                      float* __restrict__ partial) {
    int lane = threadIdx.x & 63;
    int w = threadIdx.x >> 6;
    int i = blockIdx.x * 4 + w;
    int y = labels[i];
    float h = 0.5f * ratio[0];
    const float*    ys_row = y_s + (size_t)i * C_CLS;
    const _Float16* s_row  = S   + (size_t)y * CP;

    float v[16];
    float m = -INFINITY, target = -INFINITY;
    #pragma unroll
    for (int k = 0; k < 4; k++) {
        int j = lane * 4 + 256 * k;          // multiple of 4; j<1000 => j+3<=999
        if (j < C_CLS) {
            f32x4 ys = *(const f32x4*)(ys_row + j);
            half4 sv = *(const half4*)(s_row + j);
            #pragma unroll
            for (int t = 0; t < 4; t++) {
                float val = ys[t] + h * (float)sv[t];
                v[k * 4 + t] = val;
                m = fmaxf(m, val);
                if (j + t == y) target = val;
            }
        } else {
            #pragma unroll
            for (int t = 0; t < 4; t++) v[k * 4 + t] = -INFINITY;
        }
    }
    #pragma unroll
    for (int off = 32; off; off >>= 1) m = fmaxf(m, __shfl_xor(m, off));
    float s = 0.f;
    #pragma unroll
    for (int k = 0; k < 16; k++) s += __expf(v[k] - m);  // exp(-inf)=0 for padding
    #pragma unroll
    for (int off = 32; off; off >>= 1) s += __shfl_xor(s, off);
    #pragma unroll
    for (int off = 32; off; off >>= 1) target = fmaxf(target, __shfl_xor(target, off));

    __shared__ float swn[4], sww[4];
    if (lane == 0) {
        float wgt = weights[y];
        swn[w] = wgt * ((m + logf(s)) - target);
        sww[w] = wgt;
    }
    __syncthreads();
    if (threadIdx.x == 0) {
        partial[2 * blockIdx.x]     = swn[0] + swn[1] + swn[2] + swn[3];
        partial[2 * blockIdx.x + 1] = sww[0] + sww[1] + sww[2] + sww[3];
    }
}

#define NBLK_NLL (N_SAMP / 4)

__global__ __launch_bounds__(256) void finalize_kernel(const float* __restrict__ partial,
                                                       float* __restrict__ out) {
    float a = 0.f, b = 0.f;
    for (int i = threadIdx.x; i < NBLK_NLL; i += 256) {
        a += partial[2 * i];
        b += partial[2 * i + 1];
    }
    #pragma unroll
    for (int off = 32; off; off >>= 1) { a += __shfl_xor(a, off); b += __shfl_xor(b, off); }
    __shared__ float wa[4], wb[4];
    int w = threadIdx.x >> 6;
    if ((threadIdx.x & 63) == 0) { wa[w] = a; wb[w] = b; }
    __syncthreads();
    if (threadIdx.x == 0)
        out[0] = (wa[0] + wa[1] + wa[2] + wa[3]) / (wb[0] + wb[1] + wb[2] + wb[3]);
}

extern "C" void kernel_launch(void* const* d_in, const int* in_sizes, int n_in,
                              void* d_out, int out_size, void* d_ws, size_t ws_size,
                              hipStream_t stream) {
    const float* fc      = (const float*)d_in[0];
    // d_in[1] = features_source (unused by reference)
    const float* y_s     = (const float*)d_in[2];
    const int*   labels  = (const int*)d_in[3];
    const float* ratio   = (const float*)d_in[4];
    const float* weights = (const float*)d_in[5];
    const float* cv      = (const float*)d_in[6];

    char* ws = (char*)d_ws;
    _Float16* Abuf  = (_Float16*)ws;                                  // [0, 8 MB)
    _Float16* Bbuf  = (_Float16*)(ws + (size_t)8 * 1024 * 1024);      // [8, 16 MB)
    _Float16* Spart = (_Float16*)(ws + (size_t)16 * 1024 * 1024);     // Z * 2 MB
    _Float16* S     = (_Float16*)ws;   // reuse Abuf region after gemm completes

    const bool big = ws_size >= ((size_t)32 * 1024 * 1024 + 65536);
    const int  Z   = big ? 8 : 4;
    float* part = (float*)(ws + (size_t)(16 + 2 * Z) * 1024 * 1024);  // 16 KB

    prep_kernel<<<(CP * A_DIM / 4) / 256, 256, 0, stream>>>(fc, cv, Abuf, Bbuf);
    if (big) {
        gemm_kernel<8><<<dim3(8, 8, 8), 256, 0, stream>>>(Abuf, Bbuf, Spart);
        ksum_kernel<8><<<(CP * CP / 8) / 256, 256, 0, stream>>>(Spart, S);
    } else {
        gemm_kernel<4><<<dim3(4, 8, 8), 256, 0, stream>>>(Abuf, Bbuf, Spart);
        ksum_kernel<4><<<(CP * CP / 8) / 256, 256, 0, stream>>>(Spart, S);
    }
    row_nll_kernel<<<NBLK_NLL, 256, 0, stream>>>(y_s, S, labels, ratio, weights, part);
    finalize_kernel<<<1, 256, 0, stream>>>(part, (float*)d_out);
}